// Round 15
// baseline (146.296 us; speedup 1.0000x reference)
//
#include <hip/hip_runtime.h>
#include <hip/hip_bf16.h>

#define DEV __device__ __forceinline__

typedef __attribute__((ext_vector_type(8))) short short8;
typedef __attribute__((ext_vector_type(4))) int i32x4;
typedef __attribute__((ext_vector_type(2))) int i32x2;
typedef __attribute__((ext_vector_type(4))) float f32x4;
typedef __attribute__((ext_vector_type(16))) float f32x16;

constexpr int B = 4, N = 2048, H = 8, DH = 64;
constexpr int INNER = H * DH;          // 512
constexpr int BH = B * H;              // 32
// SCALE * log2(e): QK^T yields log2-domain scores -> v_exp_f32 (2^x) directly
constexpr float QSCALE = 0.125f * 1.44269504088896f;

// ---- workspace layout (bf16 elements) ----
constexpr size_t OFF_WQKVT = 0;                               // [1536][512]
constexpr size_t OFF_WOUTT = OFF_WQKVT + (size_t)1536 * 512;  // [512][512]
constexpr size_t OFF_QT    = OFF_WOUTT + (size_t)512 * 512;   // [32][2048][128]
constexpr size_t OFF_KT    = OFF_QT + (size_t)BH * N * 128;   // [32][2048][128]
constexpr size_t OFF_VT    = OFF_KT + (size_t)BH * N * 128;   // [32][64][2048]
constexpr size_t OFF_AO    = OFF_VT + (size_t)BH * DH * N;    // [8192][512]
constexpr size_t OFF_XBF   = OFF_AO + (size_t)8192 * 512;     // [8192][512] x as bf16
constexpr size_t OFF_BBF   = OFF_AO;                          // bias bf16 (aliases AO; AO written later)

DEV short f2b(float f) {
    __hip_bfloat16 h = __float2bfloat16(f);
    return __builtin_bit_cast(short, h);
}

DEV int cvtpk(float lo, float hi) {
    int r;
    asm("v_cvt_pk_bf16_f32 %0, %1, %2" : "=v"(r) : "v"(lo), "v"(hi));
    return r;
}

DEV float fexp2(float x) {
    float r;
    asm("v_exp_f32 %0, %1" : "=v"(r) : "v"(x));
    return r;
}

DEV void plswap(int& a, int& b) {
    i32x2 r = __builtin_amdgcn_permlane32_swap(a, b, false, false);
    a = r.x; b = r.y;
}

DEV void gload16(const void* g, void* l) {
    __builtin_amdgcn_global_load_lds(
        (const __attribute__((address_space(1))) unsigned int*)g,
        (__attribute__((address_space(3))) unsigned int*)l, 16, 0, 0);
}

// ---------------- prep: weight transpose + x/bias -> bf16 ----------------
__global__ void prep_kernel(const float* __restrict__ wqkv,
                            const float* __restrict__ wout,
                            const float* __restrict__ x,
                            const float* __restrict__ bias,
                            __hip_bfloat16* __restrict__ ws) {
    __hip_bfloat16* wqkvT = ws + OFF_WQKVT;
    __hip_bfloat16* woutT = ws + OFF_WOUTT;
    short8* xbf = (short8*)(ws + OFF_XBF);
    short8* bbf = (short8*)(ws + OFF_BBF);
    int tid = blockIdx.x * blockDim.x + threadIdx.x;
    const int nconv = 8192 * 512 / 8;
    const int t1 = 512 * 1536 / 4;
    const int t2 = 512 * 512 / 4;
    const int total = 2 * nconv + t1 + t2;
    for (int i = tid; i < total; i += gridDim.x * blockDim.x) {
        if (i < 2 * nconv) {
            const float4* src = (const float4*)(i < nconv ? x : bias);
            short8* dst = i < nconv ? xbf : bbf;
            int j = i < nconv ? i : i - nconv;
            float4 v0 = src[2 * j], v1 = src[2 * j + 1];
            short8 sv;
            sv[0] = f2b(v0.x); sv[1] = f2b(v0.y); sv[2] = f2b(v0.z); sv[3] = f2b(v0.w);
            sv[4] = f2b(v1.x); sv[5] = f2b(v1.y); sv[6] = f2b(v1.z); sv[7] = f2b(v1.w);
            dst[j] = sv;
        } else if (i < 2 * nconv + t1) {
            int j = i - 2 * nconv;
            int k  = j / 384;
            int c4 = (j % 384) * 4;
            float4 v = ((const float4*)wqkv)[j];
            wqkvT[(size_t)(c4 + 0) * 512 + k] = __float2bfloat16(v.x);
            wqkvT[(size_t)(c4 + 1) * 512 + k] = __float2bfloat16(v.y);
            wqkvT[(size_t)(c4 + 2) * 512 + k] = __float2bfloat16(v.z);
            wqkvT[(size_t)(c4 + 3) * 512 + k] = __float2bfloat16(v.w);
        } else {
            int j = i - 2 * nconv - t1;
            int k  = j / 128;
            int c4 = (j % 128) * 4;
            float4 v = ((const float4*)wout)[j];
            woutT[(size_t)(c4 + 0) * 512 + k] = __float2bfloat16(v.x);
            woutT[(size_t)(c4 + 1) * 512 + k] = __float2bfloat16(v.y);
            woutT[(size_t)(c4 + 2) * 512 + k] = __float2bfloat16(v.z);
            woutT[(size_t)(c4 + 3) * 512 + k] = __float2bfloat16(v.w);
        }
    }
}

// ---------------- GEMM1: qkv = {x,bias}@w_qkv -> QT/KT/VT ----------------
// grid (64, 20): yt 0..11 = x (all 1536 cols), yt 12..19 = bias (cols 0..1023)
// BK=32, 3-buffer rotation, counted vmcnt(4) pipeline (R10 skeleton): loads stay in
// flight across barriers instead of the serial stage->drain->compute 2-phase.
__global__ __launch_bounds__(256, 3) void gemm_qkv(__hip_bfloat16* __restrict__ ws) {
    int mt = blockIdx.x, yt = blockIdx.y;
    bool src_is_bias = (yt >= 12);
    int nt = src_is_bias ? yt - 12 : yt;
    const short* A  = (const short*)(ws + (src_is_bias ? OFF_BBF : OFF_XBF));
    const short* Bt = (const short*)(ws + OFF_WQKVT);
    int m0 = mt * 128, n0 = nt * 128;
    bool isV = (!src_is_bias && nt >= 8);

    __shared__ __align__(16) short As[3][128][32];   // 3 x 8 KB
    __shared__ __align__(16) short Bs[3][128][32];   // 3 x 8 KB  (48 KB total)

    int tid  = threadIdx.x;
    int wave = tid >> 6, lane = tid & 63;
    int wrow = wave >> 1, wcol = wave & 1;
    int lg = lane >> 4, li = lane & 15;

    f32x4 acc[4][4] = {};

    // stage K-step t (k0 = t*32) into buffer bsel: A 8 chunks + B 8 chunks of 1KB;
    // wave handles 2 of each -> 4 gloads/wave/step (vmcnt granularity = 4)
    auto stage = [&](int t, int bsel) {
        int k0 = t * 32;
#pragma unroll
        for (int i = 0; i < 2; ++i) {
            int ck = wave * 2 + i;
            int r  = ck * 16 + (lane >> 2);
            int cb = (lane & 3) * 8;   // shorts within the 32-wide row
            gload16((const char*)A + ((size_t)(m0 + r) * 512 + k0 + cb) * 2,
                    (char*)&As[bsel][0][0] + ck * 1024);
            gload16((const char*)Bt + ((size_t)(n0 + r) * 512 + k0 + cb) * 2,
                    (char*)&Bs[bsel][0][0] + ck * 1024);
        }
    };

    auto compute = [&](int bsel, bool swp) {
        short8 af[4], bf[4];
#pragma unroll
        for (int m = 0; m < 4; ++m)
            af[m] = *(const short8*)(&As[bsel][wrow * 64 + m * 16 + li][lg * 8]);
#pragma unroll
        for (int n = 0; n < 4; ++n)
            bf[n] = *(const short8*)(&Bs[bsel][wcol * 64 + n * 16 + li][lg * 8]);
#pragma unroll
        for (int m = 0; m < 4; ++m)
#pragma unroll
            for (int n = 0; n < 4; ++n)
                acc[m][n] = swp
                    ? __builtin_amdgcn_mfma_f32_16x16x32_bf16(bf[n], af[m], acc[m][n], 0, 0, 0)
                    : __builtin_amdgcn_mfma_f32_16x16x32_bf16(af[m], bf[n], acc[m][n], 0, 0, 0);
    };

    // prologue: 2 steps in flight
    stage(0, 0);
    stage(1, 1);

    int bsel = 0;
    for (int t = 0; t < 16; ++t) {
        if (t < 15) asm volatile("s_waitcnt vmcnt(4)" ::: "memory");   // my stage(t) landed; stage(t+1) may fly
        else        asm volatile("s_waitcnt vmcnt(0)" ::: "memory");
        __builtin_amdgcn_s_barrier();                                  // all waves' stage(t) landed; compute(t-1) done
        __builtin_amdgcn_sched_barrier(0);
        if (t + 2 < 16) {
            int b2 = bsel + 2 >= 3 ? bsel - 1 : bsel + 2;
            stage(t + 2, b2);
        }
        if (isV) compute(bsel, false); else compute(bsel, true);
        bsel = bsel + 1 >= 3 ? 0 : bsel + 1;
    }

    __hip_bfloat16* QT = ws + OFF_QT;
    __hip_bfloat16* KT = ws + OFF_KT;
    __hip_bfloat16* VT = ws + OFF_VT;

    if (isV) {
        // original orientation: lane holds col cc (d) fixed, rows (tokens) lg*4+j
        int cc_base = n0 - 1024 + wcol * 64;
#pragma unroll
        for (int m = 0; m < 4; ++m) {
            int row0 = m0 + wrow * 64 + m * 16 + lg * 4;
            int b = row0 >> 11, nn = row0 & 2047;
#pragma unroll
            for (int n = 0; n < 4; ++n) {
                int cc = cc_base + n * 16 + li;
                int h = cc >> 6, d = cc & 63;
                int w0 = cvtpk(acc[m][n][0], acc[m][n][1]);
                int w1 = cvtpk(acc[m][n][2], acc[m][n][3]);
                short* p = (short*)VT + (size_t)((b * H + h) * DH + d) * N + nn;
                i32x2 wv = { w0, w1 };
                *(i32x2*)p = wv;
            }
        }
    } else {
        // swapped orientation: lane holds token row fixed (li), 4 consecutive cols lg*4+j
        int qkoff = src_is_bias ? 64 : 0;
        bool isQ = (n0 < 512);
#pragma unroll
        for (int m = 0; m < 4; ++m) {
            int row = m0 + wrow * 64 + m * 16 + li;
            int b = row >> 11, nn = row & 2047;
#pragma unroll
            for (int n = 0; n < 4; ++n) {
                int cc0 = n0 + wcol * 64 + n * 16 + lg * 4;
                int w0, w1;
                short* p;
                if (isQ) {
                    int h = cc0 >> 6, d0 = (cc0 & 63) + qkoff;
                    w0 = cvtpk(acc[m][n][0] * QSCALE, acc[m][n][1] * QSCALE);
                    w1 = cvtpk(acc[m][n][2] * QSCALE, acc[m][n][3] * QSCALE);
                    p = (short*)QT + ((size_t)(b * H + h) * N + nn) * 128 + d0;
                } else {
                    int c = cc0 - 512;
                    int h = c >> 6, d0 = (c & 63) + qkoff;
                    w0 = cvtpk(acc[m][n][0], acc[m][n][1]);
                    w1 = cvtpk(acc[m][n][2], acc[m][n][3]);
                    p = (short*)KT + ((size_t)(b * H + h) * N + nn) * 128 + d0;
                }
                i32x2 wv = { w0, w1 };
                *(i32x2*)p = wv;
            }
        }
    }
}

// ---------------- flash attention: 32x32 MFMA, log2 defer-max softmax, unroll-2 ----------------
// grid 512 = 8 XCD-groups x 4 bh x 16 qblocks; 4 waves x 32 q each.
__global__ __launch_bounds__(256, 3) void attn_kernel(__hip_bfloat16* __restrict__ ws) {
    int bid = blockIdx.x;
    int c   = bid & 7;
    int idx = bid >> 3;
    int bh  = (idx & 3) * 8 + c;      // 4 bh per XCD -> K/V L2-resident
    int qb  = idx >> 2;

    int wave = threadIdx.x >> 6, lane = threadIdx.x & 63;
    int li32 = lane & 31, hi = lane >> 5;
    int qr0 = qb * 128 + wave * 32;

    const short* QT  = (const short*)(ws + OFF_QT) + (size_t)bh * N * 128;
    const char*  KTg = (const char*)((const short*)(ws + OFF_KT) + (size_t)bh * N * 128);
    const char*  VTg = (const char*)((const short*)(ws + OFF_VT) + (size_t)bh * DH * N);

    __shared__ __align__(16) short Ktile[2][64][128];   // 32 KB dbuf
    __shared__ __align__(16) short Vtile[2][64][64];    // 16 KB dbuf

    short8 qf[8];
#pragma unroll
    for (int kc = 0; kc < 8; ++kc)
        qf[kc] = *(const short8*)(QT + (size_t)(qr0 + li32) * 128 + kc * 16 + hi * 8);

    float m_run = -3e38f, l_run = 0.f;   // l_run: per-lane half-row sum; cross-half add in epilogue
    f32x16 o[2] = {};

    auto stage = [&](int t, int b) {
        int kv0 = t * 64;
#pragma unroll
        for (int cc = 0; cc < 4; ++cc) {          // K: 16 KB, 4 chunks/wave
            int ck = wave * 4 + cc;
            int r  = ck * 4 + (lane >> 4);
            int cbx = (lane & 15) * 16;
            gload16(KTg + (size_t)(kv0 + r) * 256 + (cbx ^ ((r & 7) << 4)),
                    (char*)&Ktile[b][0][0] + ck * 1024);
        }
#pragma unroll
        for (int cc = 0; cc < 2; ++cc) {          // V: 8 KB, 2 chunks/wave
            int ck = wave * 2 + cc;
            int r  = ck * 8 + (lane >> 3);
            int cbx = (lane & 7) * 16;
            gload16(VTg + (size_t)r * 4096 + kv0 * 2 + (cbx ^ ((r & 7) << 4)),
                    (char*)&Vtile[b][0][0] + ck * 1024);
        }
    };

    // compile-time per-buffer base pointers -> all LDS read addresses loop-invariant
    const char* Kb0 = (const char*)&Ktile[0][0][0];
    const char* Kb1 = (const char*)&Ktile[1][0][0];
    const char* Vb0 = (const char*)&Vtile[0][0][0];
    const char* Vb1 = (const char*)&Vtile[1][0][0];

    auto tile = [&](const char* Kb, const char* Vb) {
        // S^T[kv][q]: sT[sub], kv = sub*32 + (r&3)+8*(r>>2)+4*hi, q = li32 (log2 domain)
        f32x16 sT[2] = {};
        __builtin_amdgcn_s_setprio(1);
#pragma unroll
        for (int sub = 0; sub < 2; ++sub) {
            int row = sub * 32 + li32;
            int sw  = (row & 7) << 4;
            const char* kbase = Kb + row * 256;
#pragma unroll
            for (int kc = 0; kc < 8; ++kc) {
                short8 kf = *(const short8*)(kbase + ((kc * 32 + hi * 16) ^ sw));
                sT[sub] = __builtin_amdgcn_mfma_f32_32x32x16_bf16(kf, qf[kc], sT[sub], 0, 0, 0);
            }
        }
        __builtin_amdgcn_s_setprio(0);

        // tree max over this tile (per q = li32)
        float t0[8];
#pragma unroll
        for (int j = 0; j < 8; ++j)
            t0[j] = fmaxf(fmaxf(sT[0][j], sT[0][j + 8]), fmaxf(sT[1][j], sT[1][j + 8]));
        float pm = fmaxf(fmaxf(fmaxf(t0[0], t0[1]), fmaxf(t0[2], t0[3])),
                         fmaxf(fmaxf(t0[4], t0[5]), fmaxf(t0[6], t0[7])));
        pm = fmaxf(pm, __shfl_xor(pm, 32));

        // defer-max (T13, THR=8 in log2 domain)
        if (__any(pm > m_run + 8.f)) {
            float mn = fmaxf(m_run, pm);
            float al = fexp2(m_run - mn);
#pragma unroll
            for (int a = 0; a < 2; ++a)
#pragma unroll
                for (int r = 0; r < 16; ++r) o[a][r] *= al;
            l_run *= al;
            m_run = mn;
        }

        // exp2 + pack to bf16 words
        float lsp[4] = {0.f, 0.f, 0.f, 0.f};
        int w[2][8];
#pragma unroll
        for (int sub = 0; sub < 2; ++sub)
#pragma unroll
            for (int r2 = 0; r2 < 8; ++r2) {
                float p0 = fexp2(sT[sub][2 * r2]     - m_run);
                float p1 = fexp2(sT[sub][2 * r2 + 1] - m_run);
                lsp[r2 & 3] += p0 + p1;
                w[sub][r2] = cvtpk(p0, p1);
            }
        l_run += (lsp[0] + lsp[1]) + (lsp[2] + lsp[3]);

        // P^T B-fragments via permlane32_swap (T12)
        short8 pf[2][2];
#pragma unroll
        for (int sub = 0; sub < 2; ++sub) {
            plswap(w[sub][0], w[sub][2]); plswap(w[sub][1], w[sub][3]);
            plswap(w[sub][4], w[sub][6]); plswap(w[sub][5], w[sub][7]);
            i32x4 f0 = { w[sub][0], w[sub][1], w[sub][2], w[sub][3] };
            i32x4 f1 = { w[sub][4], w[sub][5], w[sub][6], w[sub][7] };
            pf[sub][0] = __builtin_bit_cast(short8, f0);
            pf[sub][1] = __builtin_bit_cast(short8, f1);
        }

        // PV: O^T[dv][q] += V^T[dv][kv] * P^T[kv][q]
        __builtin_amdgcn_s_setprio(1);
#pragma unroll
        for (int sub = 0; sub < 2; ++sub)
#pragma unroll
            for (int ksel = 0; ksel < 2; ++ksel) {
                int cc = sub * 2 + ksel;
#pragma unroll
                for (int a = 0; a < 2; ++a) {
                    int row = a * 32 + li32;
                    int sw  = (row & 7) << 4;
                    short8 vf = *(const short8*)(Vb + row * 128 + ((cc * 32 + hi * 16) ^ sw));
                    o[a] = __builtin_amdgcn_mfma_f32_32x32x16_bf16(vf, pf[sub][ksel], o[a], 0, 0, 0);
                }
            }
        __builtin_amdgcn_s_setprio(0);

        __syncthreads();
    };

    stage(0, 0);
    __syncthreads();

    for (int t = 0; t < 32; t += 2) {
        stage(t + 1, 1);                  // t <= 30 -> t+1 <= 31, always valid
        tile(Kb0, Vb0);
        if (t + 2 < 32) stage(t + 2, 0);
        tile(Kb1, Vb1);
    }

    // epilogue: O^T -> LDS transpose -> coalesced AO rows
    l_run += __shfl_xor(l_run, 32);    // combine the two half-row sums (both halves share m_run)
    __hip_bfloat16* AO = ws + OFF_AO;
    int b = bh >> 3, h = bh & 7;
    char* tb = (char*)&Ktile[0][0][0] + wave * 4096;
    float inv = 1.f / l_run;
#pragma unroll
    for (int a = 0; a < 2; ++a)
#pragma unroll
        for (int r2 = 0; r2 < 8; ++r2) {
            int r = 2 * r2;
            int dv = (r & 3) + 8 * (r >> 2) + 4 * hi + 32 * a;
            int word = cvtpk(o[a][r] * inv, o[a][r + 1] * inv);
            *(int*)(tb + li32 * 128 + ((dv * 2) ^ ((li32 & 7) << 4))) = word;
        }
#pragma unroll
    for (int qq = 0; qq < 32; qq += 8) {
        int q = qq + (lane >> 3), seg = lane & 7;
        short8 vrow = *(const short8*)(tb + q * 128 + ((seg * 16) ^ ((q & 7) << 4)));
        *(short8*)(AO + (size_t)(b * N + qr0 + q) * INNER + h * 64 + seg * 8) = vrow;
    }
}

// ---------------- GEMM3: out = AO @ w_out + b_out (swapped operands -> float4 stores) ----------------
__global__ __launch_bounds__(256) void gemm_out(const __hip_bfloat16* __restrict__ ws_c,
                                                const float* __restrict__ bout,
                                                float* __restrict__ out) {
    const short* AO = (const short*)(ws_c + OFF_AO);
    const short* Bt = (const short*)(ws_c + OFF_WOUTT);
    int m0 = blockIdx.x * 128, n0 = blockIdx.y * 128;

    __shared__ __align__(16) short As[128][64];
    __shared__ __align__(16) short Bs[128][64];

    int tid  = threadIdx.x;
    int wave = tid >> 6, lane = tid & 63;
    int wrow = wave >> 1, wcol = wave & 1;
    int lg = lane >> 4, li = lane & 15;

    f32x4 acc[4][4] = {};

    for (int k0 = 0; k0 < 512; k0 += 64) {
#pragma unroll
        for (int i = 0; i < 4; ++i) {
            int c = wave * 4 + i;
            int r = c * 8 + (lane >> 3);
            gload16((const char*)AO + ((size_t)(m0 + r) * 512 + k0 + (lane & 7) * 8) * 2,
                    (char*)&As[0][0] + c * 1024);
            gload16((const char*)Bt + ((size_t)(n0 + r) * 512 + k0 + (lane & 7) * 8) * 2,
                    (char*)&Bs[0][0] + c * 1024);
        }
        __syncthreads();
#pragma unroll
        for (int ks = 0; ks < 2; ++ks) {
            short8 af[4], bf[4];
#pragma unroll
            for (int m = 0; m < 4; ++m)
                af[m] = *(const short8*)(&As[wrow * 64 + m * 16 + li][ks * 32 + lg * 8]);
#pragma unroll
            for (int n = 0; n < 4; ++n)
                bf[n] = *(const short8*)(&Bs[wcol * 64 + n * 16 + li][ks * 32 + lg * 8]);
#pragma unroll
            for (int m = 0; m < 4; ++m)
#pragma unroll
                for (int n = 0; n < 4; ++n)
                    acc[m][n] = __builtin_amdgcn_mfma_f32_16x16x32_bf16(bf[n], af[m], acc[m][n], 0, 0, 0);
        }
        __syncthreads();
    }

    // swapped: lane holds out-row = ...+li, 4 consecutive cols = ...+lg*4+j
    float4 bb[4];
#pragma unroll
    for (int n = 0; n < 4; ++n)
        bb[n] = *(const float4*)(bout + n0 + wcol * 64 + n * 16 + lg * 4);
#pragma unroll
    for (int m = 0; m < 4; ++m) {
        int row = m0 + wrow * 64 + m * 16 + li;
#pragma unroll
        for (int n = 0; n < 4; ++n) {
            int c0 = n0 + wcol * 64 + n * 16 + lg * 4;
            float4 v = { acc[m][n][0] + bb[n].x, acc[m][n][1] + bb[n].y,
                         acc[m][n][2] + bb[n].z, acc[m][n][3] + bb[n].w };
            *(float4*)(out + (size_t)row * 512 + c0) = v;
        }
    }
}

extern "C" void kernel_launch(void* const* d_in, const int* in_sizes, int n_in,
                              void* d_out, int out_size, void* d_ws, size_t ws_size,
                              hipStream_t stream) {
    const float* x    = (const float*)d_in[0];
    const float* bias = (const float*)d_in[1];
    const float* wqkv = (const float*)d_in[2];
    const float* wout = (const float*)d_in[3];
    const float* bout = (const float*)d_in[4];
    float* out = (float*)d_out;
    __hip_bfloat16* ws = (__hip_bfloat16*)d_ws;

    hipLaunchKernelGGL(prep_kernel, dim3(2048), dim3(256), 0, stream, wqkv, wout, x, bias, ws);
    hipLaunchKernelGGL(gemm_qkv, dim3(64, 20), dim3(256), 0, stream, ws);
    hipLaunchKernelGGL(attn_kernel, dim3(512), dim3(256), 0, stream, ws);
    hipLaunchKernelGGL(gemm_out, dim3(64, 4), dim3(256), 0, stream, (const __hip_bfloat16*)ws, bout, out);
}

// Round 16
// 138.973 us; speedup vs baseline: 1.0527x; 1.0527x over previous
//
#include <hip/hip_runtime.h>
#include <hip/hip_bf16.h>

#define DEV __device__ __forceinline__

typedef __attribute__((ext_vector_type(8))) short short8;
typedef __attribute__((ext_vector_type(4))) int i32x4;
typedef __attribute__((ext_vector_type(2))) int i32x2;
typedef __attribute__((ext_vector_type(4))) float f32x4;
typedef __attribute__((ext_vector_type(16))) float f32x16;

constexpr int B = 4, N = 2048, H = 8, DH = 64;
constexpr int INNER = H * DH;          // 512
constexpr int BH = B * H;              // 32
// SCALE * log2(e): QK^T yields log2-domain scores -> v_exp_f32 (2^x) directly
constexpr float QSCALE = 0.125f * 1.44269504088896f;

// ---- workspace layout (bf16 elements) ----
constexpr size_t OFF_WQKVT = 0;                               // [1536][512]
constexpr size_t OFF_WOUTT = OFF_WQKVT + (size_t)1536 * 512;  // [512][512]
constexpr size_t OFF_QT    = OFF_WOUTT + (size_t)512 * 512;   // [32][2048][128]
constexpr size_t OFF_KT    = OFF_QT + (size_t)BH * N * 128;   // [32][2048][128]
constexpr size_t OFF_VT    = OFF_KT + (size_t)BH * N * 128;   // [32][64][2048]
constexpr size_t OFF_AO    = OFF_VT + (size_t)BH * DH * N;    // [8192][512]
constexpr size_t OFF_XBF   = OFF_AO + (size_t)8192 * 512;     // [8192][512] x as bf16
constexpr size_t OFF_BBF   = OFF_AO;                          // bias bf16 (aliases AO; AO written later)

DEV short f2b(float f) {
    __hip_bfloat16 h = __float2bfloat16(f);
    return __builtin_bit_cast(short, h);
}

DEV int cvtpk(float lo, float hi) {
    int r;
    asm("v_cvt_pk_bf16_f32 %0, %1, %2" : "=v"(r) : "v"(lo), "v"(hi));
    return r;
}

DEV float fexp2(float x) {
    float r;
    asm("v_exp_f32 %0, %1" : "=v"(r) : "v"(x));
    return r;
}

DEV void plswap(int& a, int& b) {
    i32x2 r = __builtin_amdgcn_permlane32_swap(a, b, false, false);
    a = r.x; b = r.y;
}

DEV void gload16(const void* g, void* l) {
    __builtin_amdgcn_global_load_lds(
        (const __attribute__((address_space(1))) unsigned int*)g,
        (__attribute__((address_space(3))) unsigned int*)l, 16, 0, 0);
}

// ---------------- prep: weight transpose + x/bias -> bf16 ----------------
__global__ void prep_kernel(const float* __restrict__ wqkv,
                            const float* __restrict__ wout,
                            const float* __restrict__ x,
                            const float* __restrict__ bias,
                            __hip_bfloat16* __restrict__ ws) {
    __hip_bfloat16* wqkvT = ws + OFF_WQKVT;
    __hip_bfloat16* woutT = ws + OFF_WOUTT;
    short8* xbf = (short8*)(ws + OFF_XBF);
    short8* bbf = (short8*)(ws + OFF_BBF);
    int tid = blockIdx.x * blockDim.x + threadIdx.x;
    const int nconv = 8192 * 512 / 8;
    const int t1 = 512 * 1536 / 4;
    const int t2 = 512 * 512 / 4;
    const int total = 2 * nconv + t1 + t2;
    for (int i = tid; i < total; i += gridDim.x * blockDim.x) {
        if (i < 2 * nconv) {
            const float4* src = (const float4*)(i < nconv ? x : bias);
            short8* dst = i < nconv ? xbf : bbf;
            int j = i < nconv ? i : i - nconv;
            float4 v0 = src[2 * j], v1 = src[2 * j + 1];
            short8 sv;
            sv[0] = f2b(v0.x); sv[1] = f2b(v0.y); sv[2] = f2b(v0.z); sv[3] = f2b(v0.w);
            sv[4] = f2b(v1.x); sv[5] = f2b(v1.y); sv[6] = f2b(v1.z); sv[7] = f2b(v1.w);
            dst[j] = sv;
        } else if (i < 2 * nconv + t1) {
            int j = i - 2 * nconv;
            int k  = j / 384;
            int c4 = (j % 384) * 4;
            float4 v = ((const float4*)wqkv)[j];
            wqkvT[(size_t)(c4 + 0) * 512 + k] = __float2bfloat16(v.x);
            wqkvT[(size_t)(c4 + 1) * 512 + k] = __float2bfloat16(v.y);
            wqkvT[(size_t)(c4 + 2) * 512 + k] = __float2bfloat16(v.z);
            wqkvT[(size_t)(c4 + 3) * 512 + k] = __float2bfloat16(v.w);
        } else {
            int j = i - 2 * nconv - t1;
            int k  = j / 128;
            int c4 = (j % 128) * 4;
            float4 v = ((const float4*)wout)[j];
            woutT[(size_t)(c4 + 0) * 512 + k] = __float2bfloat16(v.x);
            woutT[(size_t)(c4 + 1) * 512 + k] = __float2bfloat16(v.y);
            woutT[(size_t)(c4 + 2) * 512 + k] = __float2bfloat16(v.z);
            woutT[(size_t)(c4 + 3) * 512 + k] = __float2bfloat16(v.w);
        }
    }
}

// ---------------- GEMM1: qkv = {x,bias}@w_qkv -> QT/KT/VT ----------------
// grid (64, 20): yt 0..11 = x (all 1536 cols), yt 12..19 = bias (cols 0..1023)
// Q/K tiles computed with SWAPPED mfma operands (lane holds token-row, 4 consec cols -> 8B stores);
// V tiles use original orientation (lane holds d-col, 4 consec tokens -> 8B stores to VT[d][n]).
__global__ __launch_bounds__(256) void gemm_qkv(__hip_bfloat16* __restrict__ ws) {
    int mt = blockIdx.x, yt = blockIdx.y;
    bool src_is_bias = (yt >= 12);
    int nt = src_is_bias ? yt - 12 : yt;
    const short* A  = (const short*)(ws + (src_is_bias ? OFF_BBF : OFF_XBF));
    const short* Bt = (const short*)(ws + OFF_WQKVT);
    int m0 = mt * 128, n0 = nt * 128;
    bool isV = (!src_is_bias && nt >= 8);

    __shared__ __align__(16) short As[128][64];
    __shared__ __align__(16) short Bs[128][64];

    int tid  = threadIdx.x;
    int wave = tid >> 6, lane = tid & 63;
    int wrow = wave >> 1, wcol = wave & 1;
    int lg = lane >> 4, li = lane & 15;

    f32x4 acc[4][4] = {};

    auto kloop = [&](bool swp) {
        for (int k0 = 0; k0 < 512; k0 += 64) {
#pragma unroll
            for (int i = 0; i < 4; ++i) {
                int c = wave * 4 + i;
                int r = c * 8 + (lane >> 3);
                gload16((const char*)A + ((size_t)(m0 + r) * 512 + k0 + (lane & 7) * 8) * 2,
                        (char*)&As[0][0] + c * 1024);
                gload16((const char*)Bt + ((size_t)(n0 + r) * 512 + k0 + (lane & 7) * 8) * 2,
                        (char*)&Bs[0][0] + c * 1024);
            }
            __syncthreads();
#pragma unroll
            for (int ks = 0; ks < 2; ++ks) {
                short8 af[4], bf[4];
#pragma unroll
                for (int m = 0; m < 4; ++m)
                    af[m] = *(const short8*)(&As[wrow * 64 + m * 16 + li][ks * 32 + lg * 8]);
#pragma unroll
                for (int n = 0; n < 4; ++n)
                    bf[n] = *(const short8*)(&Bs[wcol * 64 + n * 16 + li][ks * 32 + lg * 8]);
#pragma unroll
                for (int m = 0; m < 4; ++m)
#pragma unroll
                    for (int n = 0; n < 4; ++n)
                        acc[m][n] = swp
                            ? __builtin_amdgcn_mfma_f32_16x16x32_bf16(bf[n], af[m], acc[m][n], 0, 0, 0)
                            : __builtin_amdgcn_mfma_f32_16x16x32_bf16(af[m], bf[n], acc[m][n], 0, 0, 0);
            }
            __syncthreads();
        }
    };
    if (isV) kloop(false); else kloop(true);

    __hip_bfloat16* QT = ws + OFF_QT;
    __hip_bfloat16* KT = ws + OFF_KT;
    __hip_bfloat16* VT = ws + OFF_VT;

    if (isV) {
        // original orientation: lane holds col cc (d) fixed, rows (tokens) lg*4+j
        int cc_base = n0 - 1024 + wcol * 64;
#pragma unroll
        for (int m = 0; m < 4; ++m) {
            int row0 = m0 + wrow * 64 + m * 16 + lg * 4;
            int b = row0 >> 11, nn = row0 & 2047;
#pragma unroll
            for (int n = 0; n < 4; ++n) {
                int cc = cc_base + n * 16 + li;
                int h = cc >> 6, d = cc & 63;
                int w0 = cvtpk(acc[m][n][0], acc[m][n][1]);
                int w1 = cvtpk(acc[m][n][2], acc[m][n][3]);
                short* p = (short*)VT + (size_t)((b * H + h) * DH + d) * N + nn;
                i32x2 wv = { w0, w1 };
                *(i32x2*)p = wv;
            }
        }
    } else {
        // swapped orientation: lane holds token row fixed (li), 4 consecutive cols lg*4+j
        int qkoff = src_is_bias ? 64 : 0;
        bool isQ = (n0 < 512);
#pragma unroll
        for (int m = 0; m < 4; ++m) {
            int row = m0 + wrow * 64 + m * 16 + li;
            int b = row >> 11, nn = row & 2047;
#pragma unroll
            for (int n = 0; n < 4; ++n) {
                int cc0 = n0 + wcol * 64 + n * 16 + lg * 4;
                int w0, w1;
                short* p;
                if (isQ) {
                    int h = cc0 >> 6, d0 = (cc0 & 63) + qkoff;
                    w0 = cvtpk(acc[m][n][0] * QSCALE, acc[m][n][1] * QSCALE);
                    w1 = cvtpk(acc[m][n][2] * QSCALE, acc[m][n][3] * QSCALE);
                    p = (short*)QT + ((size_t)(b * H + h) * N + nn) * 128 + d0;
                } else {
                    int c = cc0 - 512;
                    int h = c >> 6, d0 = (c & 63) + qkoff;
                    w0 = cvtpk(acc[m][n][0], acc[m][n][1]);
                    w1 = cvtpk(acc[m][n][2], acc[m][n][3]);
                    p = (short*)KT + ((size_t)(b * H + h) * N + nn) * 128 + d0;
                }
                i32x2 wv = { w0, w1 };
                *(i32x2*)p = wv;
            }
        }
    }
}

// ---------------- flash attention: 32x32 MFMA, log2 defer-max softmax, unroll-2 ----------------
// grid 512 = 8 XCD-groups x 4 bh x 16 qblocks; 4 waves x 32 q each.
__global__ __launch_bounds__(256, 3) void attn_kernel(__hip_bfloat16* __restrict__ ws) {
    int bid = blockIdx.x;
    int c   = bid & 7;
    int idx = bid >> 3;
    int bh  = (idx & 3) * 8 + c;      // 4 bh per XCD -> K/V L2-resident
    int qb  = idx >> 2;

    int wave = threadIdx.x >> 6, lane = threadIdx.x & 63;
    int li32 = lane & 31, hi = lane >> 5;
    int qr0 = qb * 128 + wave * 32;

    const short* QT  = (const short*)(ws + OFF_QT) + (size_t)bh * N * 128;
    const char*  KTg = (const char*)((const short*)(ws + OFF_KT) + (size_t)bh * N * 128);
    const char*  VTg = (const char*)((const short*)(ws + OFF_VT) + (size_t)bh * DH * N);

    __shared__ __align__(16) short Ktile[2][64][128];   // 32 KB dbuf
    __shared__ __align__(16) short Vtile[2][64][64];    // 16 KB dbuf

    short8 qf[8];
#pragma unroll
    for (int kc = 0; kc < 8; ++kc)
        qf[kc] = *(const short8*)(QT + (size_t)(qr0 + li32) * 128 + kc * 16 + hi * 8);

    float m_run = -3e38f, l_run = 0.f;   // l_run: per-lane half-row sum; cross-half add in epilogue
    f32x16 o[2] = {};

    auto stage = [&](int t, int b) {
        int kv0 = t * 64;
#pragma unroll
        for (int cc = 0; cc < 4; ++cc) {          // K: 16 KB, 4 chunks/wave
            int ck = wave * 4 + cc;
            int r  = ck * 4 + (lane >> 4);
            int cbx = (lane & 15) * 16;
            gload16(KTg + (size_t)(kv0 + r) * 256 + (cbx ^ ((r & 7) << 4)),
                    (char*)&Ktile[b][0][0] + ck * 1024);
        }
#pragma unroll
        for (int cc = 0; cc < 2; ++cc) {          // V: 8 KB, 2 chunks/wave
            int ck = wave * 2 + cc;
            int r  = ck * 8 + (lane >> 3);
            int cbx = (lane & 7) * 16;
            gload16(VTg + (size_t)r * 4096 + kv0 * 2 + (cbx ^ ((r & 7) << 4)),
                    (char*)&Vtile[b][0][0] + ck * 1024);
        }
    };

    // compile-time per-buffer base pointers -> all LDS read addresses loop-invariant
    const char* Kb0 = (const char*)&Ktile[0][0][0];
    const char* Kb1 = (const char*)&Ktile[1][0][0];
    const char* Vb0 = (const char*)&Vtile[0][0][0];
    const char* Vb1 = (const char*)&Vtile[1][0][0];

    auto tile = [&](const char* Kb, const char* Vb) {
        // S^T[kv][q]: sT[sub], kv = sub*32 + (r&3)+8*(r>>2)+4*hi, q = li32 (log2 domain)
        f32x16 sT[2] = {};
        __builtin_amdgcn_s_setprio(1);
#pragma unroll
        for (int sub = 0; sub < 2; ++sub) {
            int row = sub * 32 + li32;
            int sw  = (row & 7) << 4;
            const char* kbase = Kb + row * 256;
#pragma unroll
            for (int kc = 0; kc < 8; ++kc) {
                short8 kf = *(const short8*)(kbase + ((kc * 32 + hi * 16) ^ sw));
                sT[sub] = __builtin_amdgcn_mfma_f32_32x32x16_bf16(kf, qf[kc], sT[sub], 0, 0, 0);
            }
        }
        __builtin_amdgcn_s_setprio(0);

        // tree max over this tile (per q = li32)
        float t0[8];
#pragma unroll
        for (int j = 0; j < 8; ++j)
            t0[j] = fmaxf(fmaxf(sT[0][j], sT[0][j + 8]), fmaxf(sT[1][j], sT[1][j + 8]));
        float pm = fmaxf(fmaxf(fmaxf(t0[0], t0[1]), fmaxf(t0[2], t0[3])),
                         fmaxf(fmaxf(t0[4], t0[5]), fmaxf(t0[6], t0[7])));
        pm = fmaxf(pm, __shfl_xor(pm, 32));

        // defer-max (T13, THR=8 in log2 domain)
        if (__any(pm > m_run + 8.f)) {
            float mn = fmaxf(m_run, pm);
            float al = fexp2(m_run - mn);
#pragma unroll
            for (int a = 0; a < 2; ++a)
#pragma unroll
                for (int r = 0; r < 16; ++r) o[a][r] *= al;
            l_run *= al;
            m_run = mn;
        }

        // exp2 + pack to bf16 words
        float lsp[4] = {0.f, 0.f, 0.f, 0.f};
        int w[2][8];
#pragma unroll
        for (int sub = 0; sub < 2; ++sub)
#pragma unroll
            for (int r2 = 0; r2 < 8; ++r2) {
                float p0 = fexp2(sT[sub][2 * r2]     - m_run);
                float p1 = fexp2(sT[sub][2 * r2 + 1] - m_run);
                lsp[r2 & 3] += p0 + p1;
                w[sub][r2] = cvtpk(p0, p1);
            }
        l_run += (lsp[0] + lsp[1]) + (lsp[2] + lsp[3]);

        // P^T B-fragments via permlane32_swap (T12)
        short8 pf[2][2];
#pragma unroll
        for (int sub = 0; sub < 2; ++sub) {
            plswap(w[sub][0], w[sub][2]); plswap(w[sub][1], w[sub][3]);
            plswap(w[sub][4], w[sub][6]); plswap(w[sub][5], w[sub][7]);
            i32x4 f0 = { w[sub][0], w[sub][1], w[sub][2], w[sub][3] };
            i32x4 f1 = { w[sub][4], w[sub][5], w[sub][6], w[sub][7] };
            pf[sub][0] = __builtin_bit_cast(short8, f0);
            pf[sub][1] = __builtin_bit_cast(short8, f1);
        }

        // PV: O^T[dv][q] += V^T[dv][kv] * P^T[kv][q]
        __builtin_amdgcn_s_setprio(1);
#pragma unroll
        for (int sub = 0; sub < 2; ++sub)
#pragma unroll
            for (int ksel = 0; ksel < 2; ++ksel) {
                int cc = sub * 2 + ksel;
#pragma unroll
                for (int a = 0; a < 2; ++a) {
                    int row = a * 32 + li32;
                    int sw  = (row & 7) << 4;
                    short8 vf = *(const short8*)(Vb + row * 128 + ((cc * 32 + hi * 16) ^ sw));
                    o[a] = __builtin_amdgcn_mfma_f32_32x32x16_bf16(vf, pf[sub][ksel], o[a], 0, 0, 0);
                }
            }
        __builtin_amdgcn_s_setprio(0);

        __syncthreads();
    };

    stage(0, 0);
    __syncthreads();

    for (int t = 0; t < 32; t += 2) {
        stage(t + 1, 1);                  // t <= 30 -> t+1 <= 31, always valid
        tile(Kb0, Vb0);
        if (t + 2 < 32) stage(t + 2, 0);
        tile(Kb1, Vb1);
    }

    // epilogue: O^T -> LDS transpose -> coalesced AO rows
    l_run += __shfl_xor(l_run, 32);    // combine the two half-row sums (both halves share m_run)
    __hip_bfloat16* AO = ws + OFF_AO;
    int b = bh >> 3, h = bh & 7;
    char* tb = (char*)&Ktile[0][0][0] + wave * 4096;
    float inv = 1.f / l_run;
#pragma unroll
    for (int a = 0; a < 2; ++a)
#pragma unroll
        for (int r2 = 0; r2 < 8; ++r2) {
            int r = 2 * r2;
            int dv = (r & 3) + 8 * (r >> 2) + 4 * hi + 32 * a;
            int word = cvtpk(o[a][r] * inv, o[a][r + 1] * inv);
            *(int*)(tb + li32 * 128 + ((dv * 2) ^ ((li32 & 7) << 4))) = word;
        }
#pragma unroll
    for (int qq = 0; qq < 32; qq += 8) {
        int q = qq + (lane >> 3), seg = lane & 7;
        short8 vrow = *(const short8*)(tb + q * 128 + ((seg * 16) ^ ((q & 7) << 4)));
        *(short8*)(AO + (size_t)(b * N + qr0 + q) * INNER + h * 64 + seg * 8) = vrow;
    }
}

// ---------------- GEMM3: out = AO @ w_out + b_out (swapped operands -> float4 stores) ----------------
__global__ __launch_bounds__(256) void gemm_out(const __hip_bfloat16* __restrict__ ws_c,
                                                const float* __restrict__ bout,
                                                float* __restrict__ out) {
    const short* AO = (const short*)(ws_c + OFF_AO);
    const short* Bt = (const short*)(ws_c + OFF_WOUTT);
    int m0 = blockIdx.x * 128, n0 = blockIdx.y * 128;

    __shared__ __align__(16) short As[128][64];
    __shared__ __align__(16) short Bs[128][64];

    int tid  = threadIdx.x;
    int wave = tid >> 6, lane = tid & 63;
    int wrow = wave >> 1, wcol = wave & 1;
    int lg = lane >> 4, li = lane & 15;

    f32x4 acc[4][4] = {};

    for (int k0 = 0; k0 < 512; k0 += 64) {
#pragma unroll
        for (int i = 0; i < 4; ++i) {
            int c = wave * 4 + i;
            int r = c * 8 + (lane >> 3);
            gload16((const char*)AO + ((size_t)(m0 + r) * 512 + k0 + (lane & 7) * 8) * 2,
                    (char*)&As[0][0] + c * 1024);
            gload16((const char*)Bt + ((size_t)(n0 + r) * 512 + k0 + (lane & 7) * 8) * 2,
                    (char*)&Bs[0][0] + c * 1024);
        }
        __syncthreads();
#pragma unroll
        for (int ks = 0; ks < 2; ++ks) {
            short8 af[4], bf[4];
#pragma unroll
            for (int m = 0; m < 4; ++m)
                af[m] = *(const short8*)(&As[wrow * 64 + m * 16 + li][ks * 32 + lg * 8]);
#pragma unroll
            for (int n = 0; n < 4; ++n)
                bf[n] = *(const short8*)(&Bs[wcol * 64 + n * 16 + li][ks * 32 + lg * 8]);
#pragma unroll
            for (int m = 0; m < 4; ++m)
#pragma unroll
                for (int n = 0; n < 4; ++n)
                    acc[m][n] = __builtin_amdgcn_mfma_f32_16x16x32_bf16(bf[n], af[m], acc[m][n], 0, 0, 0);
        }
        __syncthreads();
    }

    // swapped: lane holds out-row = ...+li, 4 consecutive cols = ...+lg*4+j
    float4 bb[4];
#pragma unroll
    for (int n = 0; n < 4; ++n)
        bb[n] = *(const float4*)(bout + n0 + wcol * 64 + n * 16 + lg * 4);
#pragma unroll
    for (int m = 0; m < 4; ++m) {
        int row = m0 + wrow * 64 + m * 16 + li;
#pragma unroll
        for (int n = 0; n < 4; ++n) {
            int c0 = n0 + wcol * 64 + n * 16 + lg * 4;
            float4 v = { acc[m][n][0] + bb[n].x, acc[m][n][1] + bb[n].y,
                         acc[m][n][2] + bb[n].z, acc[m][n][3] + bb[n].w };
            *(float4*)(out + (size_t)row * 512 + c0) = v;
        }
    }
}

extern "C" void kernel_launch(void* const* d_in, const int* in_sizes, int n_in,
                              void* d_out, int out_size, void* d_ws, size_t ws_size,
                              hipStream_t stream) {
    const float* x    = (const float*)d_in[0];
    const float* bias = (const float*)d_in[1];
    const float* wqkv = (const float*)d_in[2];
    const float* wout = (const float*)d_in[3];
    const float* bout = (const float*)d_in[4];
    float* out = (float*)d_out;
    __hip_bfloat16* ws = (__hip_bfloat16*)d_ws;

    hipLaunchKernelGGL(prep_kernel, dim3(2048), dim3(256), 0, stream, wqkv, wout, x, bias, ws);
    hipLaunchKernelGGL(gemm_qkv, dim3(64, 20), dim3(256), 0, stream, ws);
    hipLaunchKernelGGL(attn_kernel, dim3(512), dim3(256), 0, stream, ws);
    hipLaunchKernelGGL(gemm_out, dim3(64, 4), dim3(256), 0, stream, (const __hip_bfloat16*)ws, bout, out);
}